// Round 1
// baseline (204.798 us; speedup 1.0000x reference)
//
#include <hip/hip_runtime.h>

// sparsegen-lin, lam = 0.5  =>  p = sparsemax(2*x) along rows of length 2048.
// tau solves sum(max(z - tau, 0)) = 1, tau in [max(z)-1, max(z)].
// One 64-lane wave per row; row held in 32 VGPR fp32 per lane.

static constexpr float INV_ONE_MINUS_LAM = 2.0f;  // 1/(1-0.5)
static constexpr int ROWLEN = 2048;
static constexpr int WPB = 4;  // waves (rows) per 256-thread block

__global__ __launch_bounds__(256) void sparsegen_lin_kernel(
    const float* __restrict__ in, float* __restrict__ out, int nrows)
{
    const int wave = threadIdx.x >> 6;
    const int lane = threadIdx.x & 63;
    const long long row = (long long)blockIdx.x * WPB + wave;
    if (row >= nrows) return;

    const float* rp = in + row * (long long)ROWLEN;
    float* op = out + row * (long long)ROWLEN;

    // Coalesced load: lane l takes float4 at element i*256 + 4*l.
    float4 z[8];
#pragma unroll
    for (int i = 0; i < 8; ++i) {
        float4 v = *reinterpret_cast<const float4*>(rp + i * 256 + lane * 4);
        v.x *= INV_ONE_MINUS_LAM; v.y *= INV_ONE_MINUS_LAM;
        v.z *= INV_ONE_MINUS_LAM; v.w *= INV_ONE_MINUS_LAM;
        z[i] = v;
    }

    // Row max (wave butterfly reduce -> all lanes hold the max).
    float m = -3.4e38f;
#pragma unroll
    for (int i = 0; i < 8; ++i)
        m = fmaxf(m, fmaxf(fmaxf(z[i].x, z[i].y), fmaxf(z[i].z, z[i].w)));
#pragma unroll
    for (int off = 32; off >= 1; off >>= 1)
        m = fmaxf(m, __shfl_xor(m, off, 64));

    // Bisection on f(tau) = sum(max(z - tau, 0)) - 1.
    // Invariant: f(lo) >= 0 >= f(hi).
    float lo = m - 1.0f;
    float hi = m;
#pragma unroll
    for (int it = 0; it < 14; ++it) {
        const float mid = 0.5f * (lo + hi);
        float s = 0.0f;
#pragma unroll
        for (int i = 0; i < 8; ++i) {
            s += fmaxf(z[i].x - mid, 0.0f);
            s += fmaxf(z[i].y - mid, 0.0f);
            s += fmaxf(z[i].z - mid, 0.0f);
            s += fmaxf(z[i].w - mid, 0.0f);
        }
#pragma unroll
        for (int off = 32; off >= 1; off >>= 1)
            s += __shfl_xor(s, off, 64);
        if (s >= 1.0f) lo = mid; else hi = mid;  // wave-uniform branch
    }

    // Exact-support correction: S = {z > lo} is a superset of the true
    // support (lo <= tau*); extra members lie within the 2^-14 bracket, so
    // tau error <= 6e-5.
    float s = 0.0f, k = 0.0f;
#pragma unroll
    for (int i = 0; i < 8; ++i) {
        s += (z[i].x > lo) ? z[i].x : 0.0f;  k += (z[i].x > lo) ? 1.0f : 0.0f;
        s += (z[i].y > lo) ? z[i].y : 0.0f;  k += (z[i].y > lo) ? 1.0f : 0.0f;
        s += (z[i].z > lo) ? z[i].z : 0.0f;  k += (z[i].z > lo) ? 1.0f : 0.0f;
        s += (z[i].w > lo) ? z[i].w : 0.0f;  k += (z[i].w > lo) ? 1.0f : 0.0f;
    }
#pragma unroll
    for (int off = 32; off >= 1; off >>= 1) {
        s += __shfl_xor(s, off, 64);
        k += __shfl_xor(k, off, 64);
    }
    const float tau = (s - 1.0f) / fmaxf(k, 1.0f);

    // p = max(z - tau, 0), coalesced float4 stores.
#pragma unroll
    for (int i = 0; i < 8; ++i) {
        float4 p;
        p.x = fmaxf(z[i].x - tau, 0.0f);
        p.y = fmaxf(z[i].y - tau, 0.0f);
        p.z = fmaxf(z[i].z - tau, 0.0f);
        p.w = fmaxf(z[i].w - tau, 0.0f);
        *reinterpret_cast<float4*>(op + i * 256 + lane * 4) = p;
    }
}

extern "C" void kernel_launch(void* const* d_in, const int* in_sizes, int n_in,
                              void* d_out, int out_size, void* d_ws, size_t ws_size,
                              hipStream_t stream)
{
    const float* in = (const float*)d_in[0];
    float* out = (float*)d_out;
    const int total = in_sizes[0];
    const int nrows = total / ROWLEN;          // 65536 for the bench shape
    const int blocks = (nrows + WPB - 1) / WPB;
    sparsegen_lin_kernel<<<blocks, 256, 0, stream>>>(in, out, nrows);
}